// Round 3
// baseline (157.098 us; speedup 1.0000x reference)
//
#include <hip/hip_runtime.h>

#define POOL    7
#define RSTRIDE 16.0f
#define IMG_H   128
#define IMG_W   128
#define IMG_C   512
#define C4      (IMG_C / 4)   // float4s per pixel
#define NBINS   64            // 8x8 Morton grid of 16x16-px bins

typedef float f4v __attribute__((ext_vector_type(4)));

__device__ __forceinline__ int roi_bin(const float* __restrict__ roi, int i) {
    const float x = roi[i * 4 + 0];
    const float y = roi[i * 4 + 1];
    const int cx = (int)fminf(fmaxf(x * (1.0f / RSTRIDE), 0.0f), 127.0f);
    const int cy = (int)fminf(fmaxf(y * (1.0f / RSTRIDE), 0.0f), 127.0f);
    const int bx = cx >> 4, by = cy >> 4;
    // Morton interleave (by -> even bits, bx -> odd bits), 3 bits each
    return (by & 1) | ((bx & 1) << 1) | ((by & 2) << 1) |
           ((bx & 2) << 2) | ((by & 4) << 2) | ((bx & 4) << 3);
}

// One-block counting sort of RoI indices by Morton bin (~1000 elems, ~2 us).
// Permutation within a bin is atomic-order-dependent but output locations are
// keyed by RoI index, so the final output is deterministic.
__global__ __launch_bounds__(256)
void roi_sort_kernel(const float* __restrict__ roi, int N, int* __restrict__ order)
{
    __shared__ int cnt[NBINS], off[NBINS];
    const int t = threadIdx.x;
    if (t < NBINS) cnt[t] = 0;
    __syncthreads();
    for (int i = t; i < N; i += 256) atomicAdd(&cnt[roi_bin(roi, i)], 1);
    __syncthreads();
    if (t == 0) { int s = 0; for (int b = 0; b < NBINS; ++b) { off[b] = s; s += cnt[b]; } }
    __syncthreads();
    for (int i = t; i < N; i += 256) {
        const int p = atomicAdd(&off[roi_bin(roi, i)], 1);
        order[p] = i;
    }
}

// One block (128 threads) per output row (n, py). SORT path: XCD x = blockIdx%8
// processes a contiguous slice of the Morton-sorted RoI list, so concurrently
// resident RoIs on one XCD overlap spatially (L2 working set ~MBs not 32 MB).
// Output stores are non-temporal: the 98 MB write stream must not evict image
// lines from L2/L3.
template <bool SORT>
__global__ __launch_bounds__(128)
void roi_pool_kernel(const float* __restrict__ image,
                     const float* __restrict__ roi,
                     float* __restrict__ out, int N,
                     const int* __restrict__ order)
{
    int n, py;
    if (SORT) {
        // requires N % 8 == 0 (then N*7 % 8 == 0 when N%8==0)
        const int xcd = blockIdx.x & 7;
        const int j   = blockIdx.x >> 3;      // 0 .. N*7/8 - 1
        const int q   = j / POOL;
        py = j - q * POOL;
        n  = order[xcd * (N >> 3) + q];
    } else {
        n  = blockIdx.x / POOL;
        py = blockIdx.x - n * POOL;
    }

    // RoI scalar math (uniform per block -> SGPRs)
    const float x = roi[n * 4 + 0];
    const float y = roi[n * 4 + 1];
    const float w = roi[n * 4 + 2];
    const float h = roi[n * 4 + 3];

    const float r  = rintf((x - 0.5f * w) / RSTRIDE);   // col start
    const float c  = rintf((y - 0.5f * h) / RSTRIDE);   // row start
    const float wq = fmaxf(rintf(w / RSTRIDE), 1.0f);
    const float hq = fmaxf(rintf(h / RSTRIDE), 1.0f);

    // y axis for this output row
    float sy = (((float)py + 0.5f) / (float)POOL) * hq - 0.5f;
    sy = fminf(fmaxf(sy, 0.0f), hq - 1.0f);
    const float fy0 = floorf(sy);
    const float ly  = sy - fy0;
    const float fy1 = fminf(fy0 + 1.0f, hq - 1.0f);
    const int iy0 = (int)fminf(fmaxf(c + fy0, 0.0f), (float)(IMG_H - 1));
    const int iy1 = (int)fminf(fmaxf(c + fy1, 0.0f), (float)(IMG_H - 1));

    const int t = threadIdx.x;                 // channel group 0..127
    const f4v* row0 = (const f4v*)(image + (size_t)iy0 * IMG_W * IMG_C) + t;
    const f4v* row1 = (const f4v*)(image + (size_t)iy1 * IMG_W * IMG_C) + t;
    f4v* po = (f4v*)(out + ((size_t)n * (POOL * POOL) + (size_t)py * POOL) * IMG_C) + t;

#pragma unroll
    for (int px = 0; px < POOL; ++px) {
        float sx = (((float)px + 0.5f) / (float)POOL) * wq - 0.5f;
        sx = fminf(fmaxf(sx, 0.0f), wq - 1.0f);
        const float fx0 = floorf(sx);
        const float lx  = sx - fx0;
        const float fx1 = fminf(fx0 + 1.0f, wq - 1.0f);
        const int ix0 = (int)fminf(fmaxf(r + fx0, 0.0f), (float)(IMG_W - 1));
        const int ix1 = (int)fminf(fmaxf(r + fx1, 0.0f), (float)(IMG_W - 1));

        const float w00 = (1.0f - ly) * (1.0f - lx);
        const float w01 = (1.0f - ly) * lx;
        const float w10 = ly * (1.0f - lx);
        const float w11 = ly * lx;

        const f4v a  = row0[ix0 * C4];
        const f4v bb = row0[ix1 * C4];
        const f4v cc = row1[ix0 * C4];
        const f4v dd = row1[ix1 * C4];

        const f4v o = w00 * a + w01 * bb + w10 * cc + w11 * dd;
        __builtin_nontemporal_store(o, po + px * C4);
    }
}

extern "C" void kernel_launch(void* const* d_in, const int* in_sizes, int n_in,
                              void* d_out, int out_size, void* d_ws, size_t ws_size,
                              hipStream_t stream)
{
    const float* image = (const float*)d_in[0];   // (1,128,128,512) fp32
    const float* roi   = (const float*)d_in[1];   // (N,4) fp32
    float*       out   = (float*)d_out;           // (1,N,7,7,512) fp32

    const int N = in_sizes[1] / 4;                // 1000
    const int blocks = N * POOL;                  // 7000 row-blocks
    int* order = (int*)d_ws;

    const bool sortable = ((N & 7) == 0) && ws_size >= (size_t)N * sizeof(int);
    if (sortable) {
        roi_sort_kernel<<<1, 256, 0, stream>>>(roi, N, order);
        roi_pool_kernel<true><<<blocks, 128, 0, stream>>>(image, roi, out, N, order);
    } else {
        roi_pool_kernel<false><<<blocks, 128, 0, stream>>>(image, roi, out, N, order);
    }
}

// Round 4
// 150.176 us; speedup vs baseline: 1.0461x; 1.0461x over previous
//
#include <hip/hip_runtime.h>

#define POOL    7
#define RSTRIDE 16.0f
#define IMG_H   128
#define IMG_W   128
#define IMG_C   512
#define C4      (IMG_C / 4)   // float4s per pixel

typedef float f4v __attribute__((ext_vector_type(4)));

// One block (128 threads) per output row (n, py). XCD swizzle: blockIdx%8
// selects the XCD; each XCD owns a contiguous slab of RoIs so one RoI's
// source region lives in a single per-XCD L2.
// Latency attack: all 7 px coordinates are precomputed, loads issued in
// batches (16 then 12 float4 loads in flight per thread) before any blend
// math -> ~3x the outstanding-request depth of the previous version
// (VGPR 16 -> ~100, still ~5 waves/SIMD).
template <bool SWIZZLE>
__global__ __launch_bounds__(128)
void roi_pool_kernel(const float* __restrict__ image,
                     const float* __restrict__ roi,
                     float* __restrict__ out, int N)
{
    int n, py;
    if (SWIZZLE) {
        const int per   = N >> 3;
        const int xcd   = blockIdx.x & 7;
        const int local = blockIdx.x >> 3;        // 0 .. N*7/8-1
        const int q     = local / POOL;
        n  = xcd * per + q;
        py = local - q * POOL;
    } else {
        n  = blockIdx.x / POOL;
        py = blockIdx.x - n * POOL;
    }

    // RoI scalar math (uniform per block -> SGPRs)
    const float x = roi[n * 4 + 0];
    const float y = roi[n * 4 + 1];
    const float w = roi[n * 4 + 2];
    const float h = roi[n * 4 + 3];

    const float r  = rintf((x - 0.5f * w) / RSTRIDE);   // col start
    const float c  = rintf((y - 0.5f * h) / RSTRIDE);   // row start
    const float wq = fmaxf(rintf(w / RSTRIDE), 1.0f);
    const float hq = fmaxf(rintf(h / RSTRIDE), 1.0f);

    // y axis for this output row
    float sy = (((float)py + 0.5f) / (float)POOL) * hq - 0.5f;
    sy = fminf(fmaxf(sy, 0.0f), hq - 1.0f);
    const float fy0 = floorf(sy);
    const float ly  = sy - fy0;
    const float fy1 = fminf(fy0 + 1.0f, hq - 1.0f);
    const int iy0 = (int)fminf(fmaxf(c + fy0, 0.0f), (float)(IMG_H - 1));
    const int iy1 = (int)fminf(fmaxf(c + fy1, 0.0f), (float)(IMG_H - 1));

    // x axis: precompute all 7 sample positions + weights (unrolled -> regs)
    int   ix0[POOL], ix1[POOL];
    float w00[POOL], w01[POOL], w10[POOL], w11[POOL];
#pragma unroll
    for (int px = 0; px < POOL; ++px) {
        float sx = (((float)px + 0.5f) / (float)POOL) * wq - 0.5f;
        sx = fminf(fmaxf(sx, 0.0f), wq - 1.0f);
        const float fx0 = floorf(sx);
        const float lx  = sx - fx0;
        const float fx1 = fminf(fx0 + 1.0f, wq - 1.0f);
        ix0[px] = (int)fminf(fmaxf(r + fx0, 0.0f), (float)(IMG_W - 1)) * C4;
        ix1[px] = (int)fminf(fmaxf(r + fx1, 0.0f), (float)(IMG_W - 1)) * C4;
        w00[px] = (1.0f - ly) * (1.0f - lx);
        w01[px] = (1.0f - ly) * lx;
        w10[px] = ly * (1.0f - lx);
        w11[px] = ly * lx;
    }

    const int t = threadIdx.x;                 // channel group 0..127
    const f4v* row0 = (const f4v*)(image + (size_t)iy0 * IMG_W * IMG_C) + t;
    const f4v* row1 = (const f4v*)(image + (size_t)iy1 * IMG_W * IMG_C) + t;
    f4v* po = (f4v*)(out + ((size_t)n * (POOL * POOL) + (size_t)py * POOL) * IMG_C) + t;

    // Batch 1: px 0..3 — 16 loads in flight, then blend + store.
    {
        f4v A[4], B[4], C[4], D[4];
#pragma unroll
        for (int i = 0; i < 4; ++i) {
            A[i] = row0[ix0[i]];
            B[i] = row0[ix1[i]];
            C[i] = row1[ix0[i]];
            D[i] = row1[ix1[i]];
        }
#pragma unroll
        for (int i = 0; i < 4; ++i) {
            po[i * C4] = w00[i] * A[i] + w01[i] * B[i] + w10[i] * C[i] + w11[i] * D[i];
        }
    }
    // Batch 2: px 4..6 — 12 loads in flight.
    {
        f4v A[3], B[3], C[3], D[3];
#pragma unroll
        for (int i = 0; i < 3; ++i) {
            A[i] = row0[ix0[4 + i]];
            B[i] = row0[ix1[4 + i]];
            C[i] = row1[ix0[4 + i]];
            D[i] = row1[ix1[4 + i]];
        }
#pragma unroll
        for (int i = 0; i < 3; ++i) {
            po[(4 + i) * C4] = w00[4 + i] * A[i] + w01[4 + i] * B[i] +
                               w10[4 + i] * C[i] + w11[4 + i] * D[i];
        }
    }
}

extern "C" void kernel_launch(void* const* d_in, const int* in_sizes, int n_in,
                              void* d_out, int out_size, void* d_ws, size_t ws_size,
                              hipStream_t stream)
{
    const float* image = (const float*)d_in[0];   // (1,128,128,512) fp32
    const float* roi   = (const float*)d_in[1];   // (N,4) fp32
    float*       out   = (float*)d_out;           // (1,N,7,7,512) fp32

    const int N = in_sizes[1] / 4;                // 1000
    const int blocks = N * POOL;                  // 7000 row-blocks

    if ((N & 7) == 0) {
        roi_pool_kernel<true><<<blocks, 128, 0, stream>>>(image, roi, out, N);
    } else {
        roi_pool_kernel<false><<<blocks, 128, 0, stream>>>(image, roi, out, N);
    }
}